// Round 15
// baseline (303.115 us; speedup 1.0000x reference)
//
#include <hip/hip_runtime.h>

#define NODE_D 128
#define NUM_GRAPHS 64
#define SCHUNK 2048   // elements per scan block (256 thr x 8)

typedef __bf16 v8bf __attribute__((ext_vector_type(8)));
typedef __bf16 v4bf __attribute__((ext_vector_type(4)));
typedef float  v4f  __attribute__((ext_vector_type(4)));

// ---------------------------------------------------------------------------
// CSR step 1 + graph bounds, fused (grid covers max(E,N))
// ---------------------------------------------------------------------------
__global__ __launch_bounds__(256) void k_hist_bounds(
    const int* __restrict__ dst, int* deg, int E,
    const int* __restrict__ batch, int* __restrict__ gs, int N)
{
    int i = blockIdx.x * 256 + threadIdx.x;
    if (i < E) atomicAdd(&deg[dst[i]], 1);
    if (i < N) {
        if (i == 0) {
            for (int g = 0; g <= batch[0]; ++g) gs[g] = 0;
        } else {
            int b0 = batch[i - 1], b1 = batch[i];
            for (int g = b0 + 1; g <= b1; ++g) gs[g] = i;
        }
        if (i == N - 1) {
            for (int g = batch[N - 1] + 1; g <= NUM_GRAPHS; ++g) gs[g] = N;
        }
    }
}

// ---------------------------------------------------------------------------
// CSR build, step 2a: per-block partial sums of deg
// ---------------------------------------------------------------------------
__global__ __launch_bounds__(256) void k_scan_partial(
    const int* __restrict__ deg, int* partial, int N)
{
    __shared__ int sbuf[256];
    int base = blockIdx.x * SCHUNK;
    int t = threadIdx.x;
    int s = 0;
#pragma unroll
    for (int i = 0; i < 8; ++i) {
        int idx = base + i * 256 + t;
        if (idx < N) s += deg[idx];
    }
    sbuf[t] = s;
    __syncthreads();
    for (int off = 128; off > 0; off >>= 1) {
        if (t < off) sbuf[t] += sbuf[t + off];
        __syncthreads();
    }
    if (t == 0) partial[blockIdx.x] = sbuf[0];
}

// ---------------------------------------------------------------------------
// CSR build, step 2b: serial exclusive scan of block partials (nb ~ 49)
// ---------------------------------------------------------------------------
__global__ void k_scan_top(int* partial, int nb)
{
    if (threadIdx.x == 0 && blockIdx.x == 0) {
        int run = 0;
        for (int i = 0; i < nb; ++i) { int v = partial[i]; partial[i] = run; run += v; }
    }
}

// ---------------------------------------------------------------------------
// CSR build, step 2c: per-block exclusive scan -> offs, cursor
// ---------------------------------------------------------------------------
__global__ __launch_bounds__(256) void k_scan_final(
    const int* __restrict__ deg, const int* __restrict__ partial,
    int* offs, int* cursor, int N)
{
    __shared__ int sbuf[256];
    int base = blockIdx.x * SCHUNK;
    int t = threadIdx.x;
    int idx0 = base + t * 8;
    int loc[8];
    int s = 0;
#pragma unroll
    for (int i = 0; i < 8; ++i) {
        int idx = idx0 + i;
        int v = (idx < N) ? deg[idx] : 0;
        loc[i] = s;
        s += v;
    }
    sbuf[t] = s;
    __syncthreads();
    for (int off = 1; off < 256; off <<= 1) {
        int tmp = (t >= off) ? sbuf[t - off] : 0;
        __syncthreads();
        sbuf[t] += tmp;
        __syncthreads();
    }
    int pre = sbuf[t] - s + partial[blockIdx.x];
#pragma unroll
    for (int i = 0; i < 8; ++i) {
        int idx = idx0 + i;
        if (idx < N) {
            int v = pre + loc[i];
            offs[idx]   = v;
            cursor[idx] = v;
        }
    }
}

// ---------------------------------------------------------------------------
// CSR build, step 3: bucket src ids into CSR order
// ---------------------------------------------------------------------------
__global__ __launch_bounds__(256) void k_fill(
    const int* __restrict__ src, const int* __restrict__ dst,
    int* cursor, int* srcs, int E)
{
    int e = blockIdx.x * 256 + threadIdx.x;
    if (e < E) {
        int pos = atomicAdd(&cursor[dst[e]], 1);
        srcs[pos] = src[e];
    }
}

// ---------------------------------------------------------------------------
// Prep, fused: idx < n8 -> xb = bf16(x); else -> Wt1 transpose+convert.
// (W2 stays fp32: the final small GEMM uses it directly.)
// ---------------------------------------------------------------------------
__global__ __launch_bounds__(256) void k_prep_all(
    const float* __restrict__ x, unsigned short* __restrict__ xb, long n8,
    const float* __restrict__ W1l, const float* __restrict__ W1r,
    unsigned short* __restrict__ Wt1)
{
    long idx = (long)blockIdx.x * 256 + threadIdx.x;
    if (idx < n8) {
        const float* p = x + idx * 8;
        float4 v0 = *(const float4*)p;
        float4 v1 = *(const float4*)(p + 4);
        v8bf b;
        b[0] = (__bf16)v0.x; b[1] = (__bf16)v0.y; b[2] = (__bf16)v0.z; b[3] = (__bf16)v0.w;
        b[4] = (__bf16)v1.x; b[5] = (__bf16)v1.y; b[6] = (__bf16)v1.z; b[7] = (__bf16)v1.w;
        *(v8bf*)(xb + idx * 8) = b;
        return;
    }
    long w = idx - n8;                 // 0..32767
    if (w >= 32768) return;
    int k = (int)(w & 255);
    int c = (int)(w >> 8);
    float v = (k < 128) ? W1l[k * 128 + c] : W1r[(k - 128) * 128 + c];
    __bf16 b = (__bf16)v;
    Wt1[c * 256 + k] = __builtin_bit_cast(unsigned short, b);
}

// ---------------------------------------------------------------------------
// Pull-aggregate + mean (bf16 in / bf16 out, fp32 accum).
// ---------------------------------------------------------------------------
__global__ __launch_bounds__(256) void k_gather_bf(
    const unsigned short* __restrict__ Xb, const int* __restrict__ srcs,
    const int* __restrict__ offs, const int* __restrict__ deg,
    unsigned short* __restrict__ outb, int N)
{
    int node = blockIdx.x * 8 + (threadIdx.x >> 5);
    if (node >= N) return;
    int lane  = threadIdx.x & 31;
    int start = offs[node];
    int d     = deg[node];
    float a0 = 0.f, a1 = 0.f, a2 = 0.f, a3 = 0.f;
    for (int base = 0; base < d; base += 32) {
        int cnt = min(d - base, 32);
        int sid = (lane < cnt) ? srcs[start + base + lane] : 0;
        for (int j = 0; j < cnt; ++j) {
            int s = __shfl(sid, j, 32);
            v4bf v = *(const v4bf*)(Xb + (size_t)s * NODE_D + lane * 4);
            a0 += (float)v[0]; a1 += (float)v[1];
            a2 += (float)v[2]; a3 += (float)v[3];
        }
    }
    float r = 1.0f / fmaxf((float)d, 1.0f);
    v4bf o;
    o[0] = (__bf16)(a0 * r); o[1] = (__bf16)(a1 * r);
    o[2] = (__bf16)(a2 * r); o[3] = (__bf16)(a3 * r);
    *(v4bf*)(outb + (size_t)node * NODE_D + lane * 4) = o;
}

// ---------------------------------------------------------------------------
// MFMA SAGE GEMM (layer 1 only): Qb = relu([A0||A1] @ Wt1 + b1) stored bf16,
// AND S2 += segsum-by-graph of the relu'd fp32 rows (pool commutes with the
// layer-2 GEMM, so only segment sums of h are needed downstream).
// BM=64, 4 waves x 16 rows. Register partials + shfl fold + LDS overlay.
// ---------------------------------------------------------------------------
#define GROWS 64
#define GKC   64
#define GSTR  (GKC + 8)
#define PSLOTS 3

__global__ __launch_bounds__(256) void k_gemm_mfma(
    const unsigned short* __restrict__ A0,    // [N][128] bf16 aggregate
    const unsigned short* __restrict__ A1,    // [N][128] bf16 x
    const unsigned short* __restrict__ Wt,    // [128][256] bf16 bits
    const float* __restrict__ bias,           // [128] fp32
    unsigned short* __restrict__ outh,        // Qb bf16
    const int* __restrict__ batch,            // [N] sorted graph ids
    float* __restrict__ S2,                   // [64][128] segsum(h) accum
    int N)
{
    __shared__ __bf16 sA[GROWS][GSTR];        // 9.2 KB
    __shared__ __bf16 sW[128][GSTR];          // 18.4 KB

    const int t    = threadIdx.x;
    const int wave = t >> 6;
    const int lane = t & 63;
    const int l15  = lane & 15;
    const int lg   = lane >> 4;
    const int row0 = blockIdx.x * GROWS;

    v4f acc[8];
#pragma unroll
    for (int n = 0; n < 8; ++n) acc[n] = (v4f){0.f, 0.f, 0.f, 0.f};

    float bk[8];
#pragma unroll
    for (int n = 0; n < 8; ++n) bk[n] = bias[n * 16 + l15];

    for (int kc = 0; kc < 4; ++kc) {
        const int kbase = kc * GKC;
        const unsigned short* Asrc = (kbase < NODE_D) ? A0 : A1;
        const int koff = kbase & (NODE_D - 1);
#pragma unroll
        for (int i = 0; i < 2; ++i) {
            int fi = i * 256 + t;
            int r  = fi >> 3;
            int k8 = fi & 7;
            int row = row0 + r;
            v8bf v = (v8bf)(__bf16)0.f;
            if (row < N) v = *(const v8bf*)(Asrc + (size_t)row * NODE_D + koff + k8 * 8);
            *(v8bf*)&sA[r][k8 * 8] = v;
        }
#pragma unroll
        for (int i = 0; i < 4; ++i) {
            int fi = i * 256 + t;
            int c  = fi >> 3;
            int k8 = fi & 7;
            v8bf w = *(const v8bf*)((const __bf16*)Wt + c * 256 + kbase + k8 * 8);
            *(v8bf*)&sW[c][k8 * 8] = w;
        }
        __syncthreads();
#pragma unroll
        for (int ks = 0; ks < 2; ++ks) {
            const int kk = ks * 32 + lg * 8;
            v8bf a = *(const v8bf*)&sA[wave * 16 + l15][kk];
#pragma unroll
            for (int n = 0; n < 8; ++n) {
                v8bf b = *(const v8bf*)&sW[n * 16 + l15][kk];
                acc[n] = __builtin_amdgcn_mfma_f32_16x16x32_bf16(a, b, acc[n], 0, 0, 0);
            }
        }
        __syncthreads();
    }
    // ---- epilogue: relu + bf16 store + segsum partials
    const int gfirst = batch[row0 < N ? row0 : (N - 1)];
    float ps0[8], ps1[8], ps2[8];
#pragma unroll
    for (int n = 0; n < 8; ++n) { ps0[n] = 0.f; ps1[n] = 0.f; ps2[n] = 0.f; }
#pragma unroll
    for (int rr = 0; rr < 4; ++rr) {
        int row = row0 + wave * 16 + lg * 4 + rr;
        if (row < N) {
            int rel = batch[row] - gfirst;
            float v[8];
#pragma unroll
            for (int n = 0; n < 8; ++n) {
                v[n] = fmaxf(acc[n][rr] + bk[n], 0.f);
                __bf16 hb = (__bf16)v[n];
                outh[(size_t)row * NODE_D + n * 16 + l15] =
                    __builtin_bit_cast(unsigned short, hb);
            }
            if (rel == 0) {
#pragma unroll
                for (int n = 0; n < 8; ++n) ps0[n] += v[n];
            } else if (rel == 1) {
#pragma unroll
                for (int n = 0; n < 8; ++n) ps1[n] += v[n];
            } else if (rel == 2) {
#pragma unroll
                for (int n = 0; n < 8; ++n) ps2[n] += v[n];
            } else {
#pragma unroll
                for (int n = 0; n < 8; ++n)
                    atomicAdd(&S2[(gfirst + rel) * NODE_D + n * 16 + l15], v[n]);
            }
        }
    }
#pragma unroll
    for (int n = 0; n < 8; ++n) {
        ps0[n] += __shfl_xor(ps0[n], 16); ps0[n] += __shfl_xor(ps0[n], 32);
        ps1[n] += __shfl_xor(ps1[n], 16); ps1[n] += __shfl_xor(ps1[n], 32);
        ps2[n] += __shfl_xor(ps2[n], 16); ps2[n] += __shfl_xor(ps2[n], 32);
    }
    float* swsum = (float*)&sA[0][0];   // 6 KB over dead sA (9.2 KB)
    if (lg == 0) {
#pragma unroll
        for (int n = 0; n < 8; ++n) {
            swsum[(wave * PSLOTS + 0) * NODE_D + n * 16 + l15] = ps0[n];
            swsum[(wave * PSLOTS + 1) * NODE_D + n * 16 + l15] = ps1[n];
            swsum[(wave * PSLOTS + 2) * NODE_D + n * 16 + l15] = ps2[n];
        }
    }
    __syncthreads();
    for (int slot = t; slot < PSLOTS * NODE_D; slot += 256) {
        int rel = slot >> 7;
        int col = slot & 127;
        float v = swsum[(0 * PSLOTS + rel) * NODE_D + col]
                + swsum[(1 * PSLOTS + rel) * NODE_D + col]
                + swsum[(2 * PSLOTS + rel) * NODE_D + col]
                + swsum[(3 * PSLOTS + rel) * NODE_D + col];
        int g = gfirst + rel;
        if (v != 0.f && g < NUM_GRAPHS)
            atomicAdd(&S2[g * NODE_D + col], v);
    }
}

// ---------------------------------------------------------------------------
// Segment-sum of bf16 [N][128] rows by graph -> S1 fp32 [64][128].
// Grid (64 graphs x 8 splits); 8 row-lanes x 32 col-lanes (v4bf = 8B each,
// 256B/row coalesced). LDS reduce 8->1, 128 atomics/block.
// ---------------------------------------------------------------------------
__global__ __launch_bounds__(256) void k_pool_bf(
    const unsigned short* __restrict__ Pb, const int* __restrict__ gs,
    float* __restrict__ S1)
{
    __shared__ float red[8][128];
    int g  = blockIdx.x;
    int s  = blockIdx.y;              // 0..7
    int t  = threadIdx.x;
    int rl = t >> 5;                  // 0..7
    int cl = t & 31;                  // 0..31
    int r0 = gs[g], r1 = gs[g + 1];
    float a0 = 0.f, a1 = 0.f, a2 = 0.f, a3 = 0.f;
    for (int r = r0 + s * 8 + rl; r < r1; r += 64) {
        v4bf v = *(const v4bf*)(Pb + (size_t)r * NODE_D + cl * 4);
        a0 += (float)v[0]; a1 += (float)v[1];
        a2 += (float)v[2]; a3 += (float)v[3];
    }
    red[rl][cl * 4 + 0] = a0; red[rl][cl * 4 + 1] = a1;
    red[rl][cl * 4 + 2] = a2; red[rl][cl * 4 + 3] = a3;
    __syncthreads();
    if (t < 128) {
        float sum = 0.f;
#pragma unroll
        for (int i = 0; i < 8; ++i) sum += red[i][t];
        if (sum != 0.f) atomicAdd(&S1[g * NODE_D + t], sum);
    }
}

// ---------------------------------------------------------------------------
// Final tiny GEMM (fp32): out[g][c] = (S1[g]·W2l[:,c] + S2[g]·W2r[:,c])/cnt
//                                     + b2[c];  cnt==0 -> 0.
// 8192 threads, 256 serial MACs each; S broadcast, W coalesced, all L2-hot.
// ---------------------------------------------------------------------------
__global__ __launch_bounds__(256) void k_gemm_small(
    const float* __restrict__ S1, const float* __restrict__ S2,
    const float* __restrict__ W2l, const float* __restrict__ W2r,
    const float* __restrict__ b2, const int* __restrict__ gs,
    float* __restrict__ out)
{
    int idx = blockIdx.x * 256 + threadIdx.x;   // 0..8191
    int g = idx >> 7;
    int c = idx & 127;
    int cnt = gs[g + 1] - gs[g];
    float acc = 0.f;
#pragma unroll 4
    for (int k = 0; k < 128; ++k) acc += S1[g * NODE_D + k] * W2l[k * 128 + c];
#pragma unroll 4
    for (int k = 0; k < 128; ++k) acc += S2[g * NODE_D + k] * W2r[k * 128 + c];
    out[idx] = (cnt > 0) ? (acc / (float)cnt + b2[c]) : 0.f;
}

// ---------------------------------------------------------------------------
extern "C" void kernel_launch(void* const* d_in, const int* in_sizes, int n_in,
                              void* d_out, int out_size, void* d_ws, size_t ws_size,
                              hipStream_t stream)
{
    const float* x   = (const float*)d_in[0];
    const int*   ei  = (const int*)d_in[1];
    const int*   bat = (const int*)d_in[2];
    const float* W1l = (const float*)d_in[3];
    const float* b1  = (const float*)d_in[4];
    const float* W1r = (const float*)d_in[5];
    const float* W2l = (const float*)d_in[6];
    const float* b2  = (const float*)d_in[7];
    const float* W2r = (const float*)d_in[8];

    const int N = in_sizes[0] / NODE_D;
    const int E = in_sizes[1] / 2;
    const int* srcp = ei;
    const int* dstp = ei + E;
    const int nb = (N + SCHUNK - 1) / SCHUNK;

    // workspace layout (bytes):
    //   [0,       N*256)  xb  bf16
    //   [N*256,  +N*256)  Pb  bf16  (aggregate)
    //   [N*512,  +N*256)  Qb  bf16  (h)
    //   S1 [8192 f] + S2 [8192 f] + deg [N i]  (contiguous -> one memset)
    //   gs[72], offs[N], cursor[N] (+Wt1 overlay), partial, srcs[E]
    char* wsb = (char*)d_ws;
    unsigned short* xb = (unsigned short*)wsb;
    unsigned short* Pb = (unsigned short*)(wsb + (size_t)N * 256);
    unsigned short* Qb = (unsigned short*)(wsb + (size_t)N * 512);
    float* S1    = (float*)(wsb + (size_t)N * 768);
    float* S2    = S1 + NUM_GRAPHS * NODE_D;
    int* deg     = (int*)(S2 + NUM_GRAPHS * NODE_D);   // [N]
    int* gs      = deg + N;                            // [72] (65 used)
    int* offs    = gs + 72;                            // [N]
    int* cursor  = offs + N;                           // [N] (dead after k_fill)
    int* partial = cursor + N;                         // [nb]
    int* srcs    = partial + ((nb + 63) & ~63);        // [E]
    unsigned short* Wt1 = (unsigned short*)cursor;     // 64KB over dead cursor

    // one memset covers S1 + S2 + deg (contiguous)
    hipMemsetAsync(S1, 0, (2 * NUM_GRAPHS * NODE_D + N) * sizeof(int), stream);

    // ---- CSR build + graph bounds
    const int mx = (E > N ? E : N);
    k_hist_bounds<<<(mx + 255) / 256, 256, 0, stream>>>(dstp, deg, E, bat, gs, N);
    k_scan_partial<<<nb, 256, 0, stream>>>(deg, partial, N);
    k_scan_top<<<1, 64, 0, stream>>>(partial, nb);
    k_scan_final<<<nb, 256, 0, stream>>>(deg, partial, offs, cursor, N);
    k_fill<<<(E + 255) / 256, 256, 0, stream>>>(srcp, dstp, cursor, srcs, E);

    // ---- prep: x->bf16 + W1 transpose (Wt1 over dead cursor)
    long n8 = (long)N * NODE_D / 8;
    long ptot = n8 + 32768;
    k_prep_all<<<(int)((ptot + 255) / 256), 256, 0, stream>>>(
        x, xb, n8, W1l, W1r, Wt1);

    const int gblk = (N + GROWS - 1) / GROWS;
    // ---- layer 1: agg(xb) -> Pb; h = relu([Pb||xb]W1+b1) -> Qb, S2 += segsum(h)
    k_gather_bf<<<(N + 7) / 8, 256, 0, stream>>>(xb, srcs, offs, deg, Pb, N);
    k_gemm_mfma<<<gblk, 256, 0, stream>>>(Pb, xb, Wt1, b1, Qb, bat, S2, N);

    // ---- layer 2 (pooled): agg(Qb) -> Pb; S1 = segsum(Pb);
    //      out = (S1@W2l + S2@W2r)/cnt + b2
    k_gather_bf<<<(N + 7) / 8, 256, 0, stream>>>(Qb, srcs, offs, deg, Pb, N);
    dim3 pgrid(NUM_GRAPHS, 8);
    k_pool_bf<<<pgrid, 256, 0, stream>>>(Pb, gs, S1);
    k_gemm_small<<<(NUM_GRAPHS * NODE_D) / 256, 256, 0, stream>>>(
        S1, S2, W2l, W2r, b2, gs, (float*)d_out);
}